// Round 5
// baseline (321.230 us; speedup 1.0000x reference)
//
#include <hip/hip_runtime.h>

#define TSTEPS 1024
#define CH 4               // chains per block; replicated 4x across MFMA m-rows

typedef _Float16 half8  __attribute__((ext_vector_type(8)));
typedef float    f32x4  __attribute__((ext_vector_type(4)));

#define MFMA16(A_, B_, C_) __builtin_amdgcn_mfma_f32_16x16x32_f16((A_), (B_), (C_), 0, 0, 0)

__device__ __forceinline__ float fast_rcp(float x) { return __builtin_amdgcn_rcpf(x); }
__device__ __forceinline__ float fast_exp2(float x) {
#if __has_builtin(__builtin_amdgcn_exp2f)
    return __builtin_amdgcn_exp2f(x);
#else
    return exp2f(x);
#endif
}

// load 8 consecutive fp32, scale, convert to packed f16 MFMA fragment
__device__ __forceinline__ half8 load_w8s(const float* p, float s) {
    const float4 a = ((const float4*)p)[0];
    const float4 b = ((const float4*)p)[1];
    half8 r;
    r[0] = (_Float16)(s * a.x); r[1] = (_Float16)(s * a.y);
    r[2] = (_Float16)(s * a.z); r[3] = (_Float16)(s * a.w);
    r[4] = (_Float16)(s * b.x); r[5] = (_Float16)(s * b.y);
    r[6] = (_Float16)(s * b.z); r[7] = (_Float16)(s * b.w);
    return r;
}

// R18 = R17 (WIN: 429->272us; operand-swapped MFMA, row-replicated A,
// in-register preacts, 1 gate-triple/lane) + two targeted fixes from the
// R17 counter budget (tick 636cy; MfmaUtil 27.5 == worst-SIMD 291cy issue):
//  1) SIMD REBALANCE: round-robin placement (wid%4) put GRU2 (wid 4,5) on
//     SIMD 0,1 atop GRU1 waves -> per-SIMD MFMA issue 15,15,6,6 tiles
//     (291cy worst). Re-map roles: GRU1 on wid {0,1,4,5}, GRU2 on wid
//     {2,3} -> 12,12,9,9 (233cy worst). GRU2 waves sit ALONE on S2/S3;
//     their inputs h1(t-1),h2(t-2) are both barrier-ready, so their
//     ~280cy chain hides under GRU1's.
//  2) PARALLEL MFMA PARTIALS: the triple consumes only acc[0], so split
//     accumulate-chains (depth 2-3 MFMA latency) into independent
//     partials with C=0, combined by 1-2 scalar v_add_f32: critical path
//     = ONE MFMA latency + adds.
// Everything else identical to R17: 256 blocks x CH=4 chains, 384 thr,
// A[m=nl]=h1[chain nl>>2][k] (replicated), B=pre-scaled weights,
// C/D row=quad*4+reg (4 identical copies of chain=quad's preact -> use
// [0]). LDS strides 80/48 (uniform 2-way). One barrier/tick. R8 parity:
// at tick t, h1(t-1) in s_h1[(t+1)&1]; GRU2 reads h2(t-2) from s_h2[t&1],
// writes h2(t-1) to s_h2[(t+1)&1]. exp2 pre-scaled gates (R10).
__global__ __launch_bounds__(384, 1)
void gru2_encoder(const float* __restrict__ x,
                  const float* __restrict__ W_ih1,
                  const float* __restrict__ W_hh1,
                  const float* __restrict__ b_ih1,
                  const float* __restrict__ b_hh1,
                  const float* __restrict__ W_ih2,
                  const float* __restrict__ W_hh2,
                  const float* __restrict__ b_ih2,
                  const float* __restrict__ b_hh2,
                  float* __restrict__ out)
{
    const int blk  = blockIdx.x;    // 256 blocks, CH=4 chains each
    const int tid  = threadIdx.x;   // 384
    const int lane = tid & 63;
    const int wid  = tid >> 6;      // 0..5
    const int nl   = lane & 15;     // MFMA non-k lane index (unit col)
    const int quad = lane >> 4;     // 0..3 (= this lane's gate CHAIN)
    const int ac   = nl >> 2;       // chain this lane's A-row replicates
    const int chain0 = blk * CH;

    // role map (fix 1): GRU1 on wid {0,1,4,5} -> tiles {0,1,2,3};
    // GRU2 on wid {2,3} -> tiles {0,1}
    const bool isG1 = (wid < 2) || (wid >= 4);
    const int  g1t  = (wid < 2) ? wid : (wid - 2);   // GRU1 unit-tile 0..3
    const int  g2t  = wid - 2;                       // GRU2 unit-tile 0..1

    const float SNEG = -1.44269504f;       // -log2(e)
    const float SP2  =  2.88539008f;       // 2*log2(e)

    // strides padded for uniform 2-way bank access
    __shared__ __align__(16) _Float16 s_h1[2][4][80];   // [par][chain][unit64 pad80]
    __shared__ __align__(16) _Float16 s_h2[2][4][48];   // [par][chain][unit32 pad48]
    __shared__ __align__(16) _Float16 s_x[TSTEPS][4];   // x f16, [t][chain]

    // ---- one-time staging
    for (int idx = tid; idx < 4 * TSTEPS; idx += 384) {
        const int m = idx >> 10, t = idx & (TSTEPS - 1);
        s_x[t][m] = (_Float16)x[(size_t)(chain0 + m) * TSTEPS + t];
    }
    {
        _Float16* p1 = &s_h1[0][0][0];
        for (int idx = tid; idx < 2 * 4 * 80; idx += 384) p1[idx] = (_Float16)0.0f;
        _Float16* p2 = &s_h2[0][0][0];
        for (int idx = tid; idx < 2 * 4 * 48; idx += 384) p2[idx] = (_Float16)0.0f;
    }
    __syncthreads();

    const f32x4 Zf = {0.0f, 0.0f, 0.0f, 0.0f};

    if (isG1) {
        // ================= GRU1, unit-tile g1t: units g1t*16+nl =================
        const int un = g1t * 16 + nl;        // this lane's output unit (n-col)
        // weights as B operand: B[k=quad*8+jj][n=nl] = W_hh1[un][k] (pre-scaled)
        const half8 Br0 = load_w8s(W_hh1 + (size_t)(un)        * 64 + quad * 8,      SNEG);
        const half8 Br1 = load_w8s(W_hh1 + (size_t)(un)        * 64 + 32 + quad * 8, SNEG);
        const half8 Bz0 = load_w8s(W_hh1 + (size_t)(64 + un)   * 64 + quad * 8,      SNEG);
        const half8 Bz1 = load_w8s(W_hh1 + (size_t)(64 + un)   * 64 + 32 + quad * 8, SNEG);
        const half8 Bn0 = load_w8s(W_hh1 + (size_t)(128 + un)  * 64 + quad * 8,      SP2);
        const half8 Bn1 = load_w8s(W_hh1 + (size_t)(128 + un)  * 64 + 32 + quad * 8, SP2);
        // bias depends on unit (col) only -> splat; carried in first partial
        const float cr = SNEG * (b_ih1[un] + b_hh1[un]);
        const float cz = SNEG * (b_ih1[64 + un] + b_hh1[64 + un]);
        const float cn = SP2 * b_hh1[128 + un];
        const f32x4 Cr = {cr, cr, cr, cr};
        const f32x4 Cz = {cz, cz, cz, cz};
        const f32x4 Cn = {cn, cn, cn, cn};
        // x-path scalars for this lane's unit
        const float twr = SNEG * W_ih1[un];
        const float twz = SNEG * W_ih1[64 + un];
        const float twn = SP2  * W_ih1[128 + un];
        const float tbn = SP2  * b_ih1[128 + un];

        float h1s = 0.0f;   // h1[chain=quad][unit=un]

        for (int t = 0; t <= TSTEPS; ++t) {
            if (t < TSTEPS) {
                const int pr = (t + 1) & 1;
                // A = h1(t-1), chain replicated over 4 rows: A[m=nl] = h1[nl>>2][k]
                const half8 A0 = *(const half8*)&s_h1[pr][ac][quad * 8];
                const half8 A1 = *(const half8*)&s_h1[pr][ac][32 + quad * 8];
                // parallel partials (fix 2): no MFMA->MFMA chains
                const f32x4 aRa = MFMA16(A0, Br0, Cr);
                const f32x4 aRb = MFMA16(A1, Br1, Zf);
                const f32x4 aZa = MFMA16(A0, Bz0, Cz);
                const f32x4 aZb = MFMA16(A1, Bz1, Zf);
                const f32x4 aNa = MFMA16(A0, Bn0, Cn);
                const f32x4 aNb = MFMA16(A1, Bn1, Zf);
                const float pR = aRa[0] + aRb[0];
                const float pZ = aZa[0] + aZb[0];
                const float pN = aNa[0] + aNb[0];
                const float xv = (float)s_x[t][quad];
                const float ea = fast_exp2(fmaf(twr, xv, pR));   // e^{-ar}
                const float eb = fast_exp2(fmaf(twz, xv, pZ));   // e^{-az}
                const float d1 = 1.0f + ea, d2 = 1.0f + eb;
                const float inv = fast_rcp(d1 * d2);
                const float rg = d2 * inv, zg = d1 * inv;
                const float nx = fmaf(twn, xv, tbn);
                const float ec = fast_exp2(fmaf(rg, pN, nx));    // e^{2an}
                const float nn = fmaf(-2.0f, fast_rcp(ec + 1.0f), 1.0f);
                h1s = nn + zg * (h1s - nn);
                s_h1[t & 1][quad][un] = (_Float16)h1s;
            }
            __syncthreads();
        }
    } else {
        // ================= GRU2, unit-tile g2t: units g2t*16+nl, one step behind
        const int vn = g2t * 16 + nl;        // this lane's output unit (n-col)
        const half8 BiR0 = load_w8s(W_ih2 + (size_t)(vn)      * 64 + quad * 8,      SNEG);
        const half8 BiR1 = load_w8s(W_ih2 + (size_t)(vn)      * 64 + 32 + quad * 8, SNEG);
        const half8 BiZ0 = load_w8s(W_ih2 + (size_t)(32 + vn) * 64 + quad * 8,      SNEG);
        const half8 BiZ1 = load_w8s(W_ih2 + (size_t)(32 + vn) * 64 + 32 + quad * 8, SNEG);
        const half8 BiN0 = load_w8s(W_ih2 + (size_t)(64 + vn) * 64 + quad * 8,      SP2);
        const half8 BiN1 = load_w8s(W_ih2 + (size_t)(64 + vn) * 64 + 32 + quad * 8, SP2);
        const half8 BhR  = load_w8s(W_hh2 + (size_t)(vn)      * 32 + quad * 8,      SNEG);
        const half8 BhZ  = load_w8s(W_hh2 + (size_t)(32 + vn) * 32 + quad * 8,      SNEG);
        const half8 BhN  = load_w8s(W_hh2 + (size_t)(64 + vn) * 32 + quad * 8,      SP2);
        const float gr  = SNEG * (b_ih2[vn] + b_hh2[vn]);
        const float gz  = SNEG * (b_ih2[32 + vn] + b_hh2[32 + vn]);
        const float gnx = SP2 * b_ih2[64 + vn];
        const float gnh = SP2 * b_hh2[64 + vn];
        const f32x4 Gr  = {gr, gr, gr, gr};
        const f32x4 Gz  = {gz, gz, gz, gz};
        const f32x4 Gnx = {gnx, gnx, gnx, gnx};
        const f32x4 Gnh = {gnh, gnh, gnh, gnh};

        float h2s = 0.0f;   // h2[chain=quad][unit=vn]

        for (int t = 0; t <= TSTEPS; ++t) {
            if (t >= 1) {
                const int pA = (t + 1) & 1;            // parity of h1(t-1)
                const half8 A0 = *(const half8*)&s_h1[pA][ac][quad * 8];
                const half8 A1 = *(const half8*)&s_h1[pA][ac][32 + quad * 8];
                const half8 Ah = *(const half8*)&s_h2[t & 1][ac][quad * 8];   // h2(t-2)
                // parallel partials (fix 2)
                const f32x4 aRa = MFMA16(A0, BiR0, Gr);
                const f32x4 aRb = MFMA16(A1, BiR1, Zf);
                const f32x4 aRc = MFMA16(Ah, BhR, Zf);
                const f32x4 aZa = MFMA16(A0, BiZ0, Gz);
                const f32x4 aZb = MFMA16(A1, BiZ1, Zf);
                const f32x4 aZc = MFMA16(Ah, BhZ, Zf);
                const f32x4 aNxa = MFMA16(A0, BiN0, Gnx);
                const f32x4 aNxb = MFMA16(A1, BiN1, Zf);
                const f32x4 aNh  = MFMA16(Ah, BhN, Gnh);
                const float pR  = aRa[0] + aRb[0] + aRc[0];
                const float pZ  = aZa[0] + aZb[0] + aZc[0];
                const float pNx = aNxa[0] + aNxb[0];
                const float pNh = aNh[0];
                const float ea = fast_exp2(pR);
                const float eb = fast_exp2(pZ);
                const float d1 = 1.0f + ea, d2 = 1.0f + eb;
                const float inv = fast_rcp(d1 * d2);
                const float rg = d2 * inv, zg = d1 * inv;
                const float ec = fast_exp2(fmaf(rg, pNh, pNx));
                const float n2 = fmaf(-2.0f, fast_rcp(ec + 1.0f), 1.0f);
                h2s = n2 + zg * (h2s - n2);
                s_h2[(t + 1) & 1][quad][vn] = (_Float16)h2s;   // h2(t-1)
            }
            __syncthreads();
        }

        // lane holds h2 for (chain=quad, unit=vn): coalesced b32 stores
        out[(size_t)(chain0 + quad) * 32 + vn] = h2s;
    }
}

extern "C" void kernel_launch(void* const* d_in, const int* in_sizes, int n_in,
                              void* d_out, int out_size, void* d_ws, size_t ws_size,
                              hipStream_t stream) {
    const float* x     = (const float*)d_in[0];
    const float* W_ih1 = (const float*)d_in[1];
    const float* W_hh1 = (const float*)d_in[2];
    const float* b_ih1 = (const float*)d_in[3];
    const float* b_hh1 = (const float*)d_in[4];
    const float* W_ih2 = (const float*)d_in[5];
    const float* W_hh2 = (const float*)d_in[6];
    const float* b_ih2 = (const float*)d_in[7];
    const float* b_hh2 = (const float*)d_in[8];
    float* out = (float*)d_out;

    gru2_encoder<<<dim3(1024 / CH), dim3(384), 0, stream>>>(
        x, W_ih1, W_hh1, b_ih1, b_hh1, W_ih2, W_hh2, b_ih2, b_hh2, out);
}